// Round 10
// baseline (454.616 us; speedup 1.0000x reference)
//
#include <hip/hip_runtime.h>

typedef __bf16 bf16;
typedef __attribute__((ext_vector_type(4))) float f32x4;
typedef __attribute__((ext_vector_type(8))) __bf16 bf16x8;
typedef __attribute__((ext_vector_type(4))) __bf16 bf16x4;

#define HIDDEN 2048
#define L_SEQ 2048
#define NHEADS 8
#define NKV 4
#define HDIM 256

// async global->LDS 16B (dest must be linear: wave-uniform base + lane*16)
__device__ __forceinline__ void gload16(const bf16* g, void* l) {
  __builtin_amdgcn_global_load_lds((const __attribute__((address_space(1))) void*)g,
                                   (__attribute__((address_space(3))) void*)l, 16, 0, 0);
}

// Barrier with EXPLICIT drain of this wave's outstanding LDS reads (lgkmcnt)
// and global->LDS writes (vmcnt) before signaling. Round-9's plain
// __syncthreads() raced intermittently: compiler may defer a ds_read's
// waitcnt to its consuming MFMA, letting a wave cross the barrier with V-tile
// reads in flight while other waves' global_load_lds overwrite the buffer.
__device__ __forceinline__ void hard_barrier() {
  __builtin_amdgcn_sched_barrier(0);
  asm volatile("s_waitcnt vmcnt(0) lgkmcnt(0)" ::: "memory");
  __builtin_amdgcn_s_barrier();
  __builtin_amdgcn_sched_barrier(0);
}

// ---------------- fp32 -> bf16 cast (vectorized) ----------------
__global__ __launch_bounds__(256) void cast_bf16_kernel(const float* __restrict__ in,
                                                        bf16* __restrict__ out, int n4) {
  int i = blockIdx.x * 256 + threadIdx.x;
  if (i >= n4) return;
  float4 v = ((const float4*)in)[i];
  bf16x4 o;
  o[0] = (bf16)v.x; o[1] = (bf16)v.y; o[2] = (bf16)v.z; o[3] = (bf16)v.w;
  ((bf16x4*)out)[i] = o;
}

// ---------------- GEMM: C = A @ B^T (unchanged, stable since r4) ----------------
template <int OUT_BF16>
__global__ __launch_bounds__(256) void gemm_bt(const bf16* __restrict__ A,
                                               const bf16* __restrict__ B,
                                               void* __restrict__ C,
                                               int M, int N, int K) {
  __shared__ __attribute__((aligned(16))) bf16 As[128 * 64];
  __shared__ __attribute__((aligned(16))) bf16 Bs[128 * 64];
  const int tid = threadIdx.x;
  const int lane = tid & 63;
  const int wid = tid >> 6;
  const int m0 = blockIdx.y * 128;
  const int n0 = blockIdx.x * 128;
  const int wm = (wid >> 1) * 64;
  const int wn = (wid & 1) * 64;

  const int srow = tid >> 3;
  const int scolb = (tid & 7) * 16;

  f32x4 acc[4][4];
#pragma unroll
  for (int i = 0; i < 4; ++i)
#pragma unroll
    for (int j = 0; j < 4; ++j) acc[i][j] = (f32x4){0.f, 0.f, 0.f, 0.f};

  for (int k0 = 0; k0 < K; k0 += 64) {
    __syncthreads();
#pragma unroll
    for (int c = 0; c < 4; ++c) {
      int row = c * 32 + srow;
      int gcol = (scolb ^ ((row & 7) << 4)) >> 1;
      gload16(A + (size_t)(m0 + row) * K + k0 + gcol, (char*)As + row * 128 + scolb);
      gload16(B + (size_t)(n0 + row) * K + k0 + gcol, (char*)Bs + row * 128 + scolb);
    }
    __syncthreads();
#pragma unroll
    for (int kk = 0; kk < 2; ++kk) {
      bf16x8 a[4], b[4];
      int colb = kk * 64 + (lane >> 4) * 16;
#pragma unroll
      for (int i = 0; i < 4; ++i) {
        int row = wm + i * 16 + (lane & 15);
        a[i] = *(const bf16x8*)((const char*)As + row * 128 + (colb ^ ((row & 7) << 4)));
      }
#pragma unroll
      for (int j = 0; j < 4; ++j) {
        int row = wn + j * 16 + (lane & 15);
        b[j] = *(const bf16x8*)((const char*)Bs + row * 128 + (colb ^ ((row & 7) << 4)));
      }
#pragma unroll
      for (int i = 0; i < 4; ++i)
#pragma unroll
        for (int j = 0; j < 4; ++j)
          acc[i][j] = __builtin_amdgcn_mfma_f32_16x16x32_bf16(a[i], b[j], acc[i][j], 0, 0, 0);
    }
  }
#pragma unroll
  for (int i = 0; i < 4; ++i)
#pragma unroll
    for (int j = 0; j < 4; ++j)
#pragma unroll
      for (int r = 0; r < 4; ++r) {
        int m = m0 + wm + i * 16 + ((lane >> 4) << 2) + r;
        int n = n0 + wn + j * 16 + (lane & 15);
        float v = acc[i][j][r];
        if (OUT_BF16)
          ((bf16*)C)[(size_t)m * N + n] = (bf16)v;
        else
          ((float*)C)[(size_t)m * N + n] = v;
      }
}

// ---------------- per-head RMSNorm + relayout (unchanged) ----------------
__global__ __launch_bounds__(256) void qknorm_kernel(const bf16* __restrict__ qkv,
                                                     const float* __restrict__ qnw,
                                                     const float* __restrict__ knw,
                                                     bf16* __restrict__ Q,
                                                     bf16* __restrict__ K,
                                                     bf16* __restrict__ Vt) {
  int w = threadIdx.x >> 6, lane = threadIdx.x & 63;
  int vec = blockIdx.x * 4 + w;
  int row = vec >> 4, sub = vec & 15;
  int b = row >> 11, l = row & 2047;
  const bf16* src = qkv + (size_t)row * 4096 + sub * 256 + lane * 4;
  bf16x4 v = *(const bf16x4*)src;
  float f[4];
#pragma unroll
  for (int j = 0; j < 4; ++j) f[j] = (float)v[j];

  if (sub < 12) {
    float ss = f[0] * f[0] + f[1] * f[1] + f[2] * f[2] + f[3] * f[3];
#pragma unroll
    for (int off = 1; off < 64; off <<= 1) ss += __shfl_xor(ss, off);
    float rs = rsqrtf(ss * (1.0f / 256.0f) + 1e-6f);
    if (sub < 8) {
      rs *= 0.0625f;
      bf16x4 o;
#pragma unroll
      for (int j = 0; j < 4; ++j) o[j] = (bf16)(f[j] * rs * qnw[lane * 4 + j]);
      *(bf16x4*)(Q + ((size_t)(b * 8 + sub) * 2048 + l) * 256 + lane * 4) = o;
    } else {
      bf16x4 o;
#pragma unroll
      for (int j = 0; j < 4; ++j) o[j] = (bf16)(f[j] * rs * knw[lane * 4 + j]);
      *(bf16x4*)(K + ((size_t)(b * 4 + (sub - 8)) * 2048 + l) * 256 + lane * 4) = o;
    }
  } else {
    bf16* dst = Vt + (size_t)(b * 4 + (sub - 12)) * 256 * 2048 + l;
#pragma unroll
    for (int j = 0; j < 4; ++j) dst[(size_t)(lane * 4 + j) * 2048] = v[j];
  }
}

// ---------------- flash attention (causal, GQA, LDS-staged K/V) ----------------
// 256 blocks = B(2) x KV(4) x pair(32); block does tiles t=p and t=63-p
// (33 kb-steps total for every p -> perfectly balanced).
// 4 waves: wave w -> head_sub = w&1, row-half = w>>1 (16 q-rows each).
// SINGLE-buffered K/V (73 KB LDS -> 2 blocks/CU, 2 waves/SIMD): staging
// latency hidden by the co-resident block (cross-block TLP). hard_barrier
// (explicit vmcnt/lgkmcnt drain) makes the single-buffer schedule race-free.
//   Ks: [64][256] rows 512B, chunk swizzle c^=(row&7)   at smem+0
//   Vs: [256][64] rows 128B (d-major from Vt), same swz at smem+32K
//   P : [4][16][72] bf16                                at smem+64K
__global__ __launch_bounds__(256, 1) void attn_kernel(const bf16* __restrict__ Q,
                                                      const bf16* __restrict__ K,
                                                      const bf16* __restrict__ Vt,
                                                      bf16* __restrict__ Out) {
  extern __shared__ __attribute__((aligned(16))) char smem[];
  bf16* PL = (bf16*)(smem + 65536);

  const int tid = threadIdx.x;
  const int lane = tid & 63;
  const int w = tid >> 6;
  const int head_sub = w & 1;
  const int half = w >> 1;
  const int bid = blockIdx.x;
  const int p = bid & 31;
  const int kh = (bid >> 5) & 3;
  const int b = bid >> 7;
  const int head = kh * 2 + head_sub;
  const int l15 = lane & 15;
  const int l4 = lane >> 4;
  const int koff = l4 * 8;
  bf16* Pw = PL + w * 16 * 72;

  const bf16* Kp = K + (size_t)(b * 4 + kh) * 2048 * 256;
  const bf16* Vp = Vt + (size_t)(b * 4 + kh) * 256 * 2048;

#pragma unroll
  for (int ph = 0; ph < 2; ++ph) {
    const int t = ph ? 63 - p : p;
    const int nkb = (t >> 1) + 1;
    const int q0 = t * 32 + half * 16;  // this wave's first q row

    const bf16* Qp = Q + ((size_t)(b * 8 + head) * 2048 + q0) * 256;
    // Q fragments: 16 rows x 256, A-layout
    bf16x8 qf[8];
#pragma unroll
    for (int c = 0; c < 8; ++c)
      qf[c] = *(const bf16x8*)(Qp + (size_t)l15 * 256 + c * 32 + koff);

    f32x4 o[16];
#pragma unroll
    for (int dt = 0; dt < 16; ++dt) o[dt] = (f32x4){0.f, 0.f, 0.f, 0.f};
    float mrow[4], lrow[4];
#pragma unroll
    for (int r = 0; r < 4; ++r) { mrow[r] = -__builtin_inff(); lrow[r] = 0.f; }

    for (int kb = 0; kb < nkb; ++kb) {
      // ---- stage K,V tile kb (single buffer, hard-fenced) ----
      hard_barrier();  // previous tile fully consumed by ALL waves
      const int kv0 = kb * 64;
#pragma unroll
      for (int i = 0; i < 8; ++i) {
        int cid = i * 256 + tid;
        int row = cid >> 5, c = cid & 31;
        gload16(Kp + (size_t)(kv0 + row) * 256 + ((c ^ (row & 7)) << 3), smem + cid * 16);
      }
#pragma unroll
      for (int i = 0; i < 8; ++i) {
        int cid = i * 256 + tid;
        int row = cid >> 3, c = cid & 7;
        gload16(Vp + (size_t)row * 2048 + kv0 + ((c ^ (row & 7)) << 3),
                smem + 32768 + cid * 16);
      }
      hard_barrier();  // staged data landed (vmcnt drained by every wave)

      // ---- S = Q K^T : 16 q-rows x 64 keys ----
      f32x4 s[4];
#pragma unroll
      for (int kt = 0; kt < 4; ++kt) s[kt] = (f32x4){0.f, 0.f, 0.f, 0.f};
#pragma unroll
      for (int kt = 0; kt < 4; ++kt) {
        int row = kt * 16 + l15;
        const char* kr = smem + row * 512;
        bf16x8 kf[8];
#pragma unroll
        for (int kk = 0; kk < 8; ++kk) {
          int c = (kk * 4 + l4) ^ (row & 7);
          kf[kk] = *(const bf16x8*)(kr + c * 16);
        }
#pragma unroll
        for (int kk = 0; kk < 8; ++kk)
          s[kt] = __builtin_amdgcn_mfma_f32_16x16x32_bf16(qf[kk], kf[kk], s[kt], 0, 0, 0);
      }
      if (kb == nkb - 1) {  // diagonal block: causal mask
#pragma unroll
        for (int kt = 0; kt < 4; ++kt) {
          int key = kb * 64 + kt * 16 + l15;
#pragma unroll
          for (int r = 0; r < 4; ++r) {
            int qg = q0 + (l4 << 2) + r;
            if (key > qg) s[kt][r] = -__builtin_inff();
          }
        }
      }
      // ---- online softmax with defer-max ----
      float rm[4];
#pragma unroll
      for (int r = 0; r < 4; ++r) {
        float m = fmaxf(fmaxf(s[0][r], s[1][r]), fmaxf(s[2][r], s[3][r]));
#pragma unroll
        for (int off = 1; off < 16; off <<= 1) m = fmaxf(m, __shfl_xor(m, off));
        rm[r] = m;
      }
      bool small = (rm[0] - mrow[0] <= 8.f) && (rm[1] - mrow[1] <= 8.f) &&
                   (rm[2] - mrow[2] <= 8.f) && (rm[3] - mrow[3] <= 8.f);
      if (__all(small)) {
        float rsum[4] = {0.f, 0.f, 0.f, 0.f};
#pragma unroll
        for (int kt = 0; kt < 4; ++kt)
#pragma unroll
          for (int r = 0; r < 4; ++r) {
            float pe = __expf(s[kt][r] - mrow[r]);
            s[kt][r] = pe;
            rsum[r] += pe;
          }
#pragma unroll
        for (int r = 0; r < 4; ++r) {
#pragma unroll
          for (int off = 1; off < 16; off <<= 1) rsum[r] += __shfl_xor(rsum[r], off);
          lrow[r] += rsum[r];
        }
      } else {
        float mnew[4], scl[4], rsum[4];
#pragma unroll
        for (int r = 0; r < 4; ++r) {
          mnew[r] = fmaxf(mrow[r], rm[r]);
          scl[r] = __expf(mrow[r] - mnew[r]);
          rsum[r] = 0.f;
        }
#pragma unroll
        for (int kt = 0; kt < 4; ++kt)
#pragma unroll
          for (int r = 0; r < 4; ++r) {
            float pe = __expf(s[kt][r] - mnew[r]);
            s[kt][r] = pe;
            rsum[r] += pe;
          }
#pragma unroll
        for (int r = 0; r < 4; ++r) {
#pragma unroll
          for (int off = 1; off < 16; off <<= 1) rsum[r] += __shfl_xor(rsum[r], off);
          lrow[r] = lrow[r] * scl[r] + rsum[r];
          mrow[r] = mnew[r];
        }
#pragma unroll
        for (int dt = 0; dt < 16; ++dt)
#pragma unroll
          for (int r = 0; r < 4; ++r) o[dt][r] *= scl[r];
      }
      // ---- P -> LDS (wave-private) -> A-frags ----
#pragma unroll
      for (int kt = 0; kt < 4; ++kt)
#pragma unroll
        for (int r = 0; r < 4; ++r)
          Pw[((l4 << 2) + r) * 72 + kt * 16 + l15] = (bf16)s[kt][r];
      bf16x8 pa[2];
#pragma unroll
      for (int kk2 = 0; kk2 < 2; ++kk2)
        pa[kk2] = *(const bf16x8*)&Pw[l15 * 72 + kk2 * 32 + koff];
      // ---- O += P V (V frags from LDS) ----
#pragma unroll
      for (int g = 0; g < 4; ++g) {
        bf16x8 vf[8];
#pragma unroll
        for (int tt = 0; tt < 4; ++tt) {
          int row = (g * 4 + tt) * 16 + l15;
          const char* vr = smem + 32768 + row * 128;
          int c0 = l4 ^ (row & 7);
          int c1 = (4 + l4) ^ (row & 7);
          vf[tt * 2] = *(const bf16x8*)(vr + c0 * 16);
          vf[tt * 2 + 1] = *(const bf16x8*)(vr + c1 * 16);
        }
#pragma unroll
        for (int tt = 0; tt < 4; ++tt) {
          int dt = g * 4 + tt;
          o[dt] = __builtin_amdgcn_mfma_f32_16x16x32_bf16(pa[0], vf[tt * 2], o[dt], 0, 0, 0);
          o[dt] = __builtin_amdgcn_mfma_f32_16x16x32_bf16(pa[1], vf[tt * 2 + 1], o[dt], 0, 0, 0);
        }
      }
    }
    // ---- epilogue for this tile ----
    float rcp[4];
#pragma unroll
    for (int r = 0; r < 4; ++r) rcp[r] = 1.0f / lrow[r];
#pragma unroll
    for (int dt = 0; dt < 16; ++dt)
#pragma unroll
      for (int r = 0; r < 4; ++r) {
        int qg = q0 + (l4 << 2) + r;
        Out[(size_t)(b * 2048 + qg) * 2048 + head * 256 + dt * 16 + l15] =
            (bf16)(o[dt][r] * rcp[r]);
      }
  }
}

// ---------------- launch ----------------
extern "C" void kernel_launch(void* const* d_in, const int* in_sizes, int n_in,
                              void* d_out, int out_size, void* d_ws, size_t ws_size,
                              hipStream_t stream) {
  const float* hidden = (const float*)d_in[0];
  const float* q_w = (const float*)d_in[1];
  const float* k_w = (const float*)d_in[2];
  const float* v_w = (const float*)d_in[3];
  const float* o_w = (const float*)d_in[4];
  const float* qnw = (const float*)d_in[5];
  const float* knw = (const float*)d_in[6];

  char* ws = (char*)d_ws;
  const size_t MB = (size_t)1 << 20;
  bf16* h_bf  = (bf16*)(ws + 0 * MB);    // 16 MiB  [4096][2048]
  bf16* wqkv  = (bf16*)(ws + 16 * MB);   // 16 MiB  [4096][2048]
  bf16* wo    = (bf16*)(ws + 32 * MB);   // 8 MiB   [2048][2048]
  bf16* qkv   = (bf16*)(ws + 40 * MB);   // 32 MiB  [4096][4096]
  bf16* aout  = qkv;                     // reuse: [4096][2048]
  bf16* Qb    = (bf16*)(ws + 72 * MB);   // 16 MiB
  bf16* Kb    = (bf16*)(ws + 88 * MB);   // 8 MiB
  bf16* Vt    = (bf16*)(ws + 96 * MB);   // 8 MiB

  cast_bf16_kernel<<<8192, 256, 0, stream>>>(hidden, h_bf, 2097152);
  cast_bf16_kernel<<<4096, 256, 0, stream>>>(q_w, wqkv, 1048576);
  cast_bf16_kernel<<<2048, 256, 0, stream>>>(k_w, wqkv + (size_t)2048 * 2048, 524288);
  cast_bf16_kernel<<<2048, 256, 0, stream>>>(v_w, wqkv + (size_t)3072 * 2048, 524288);
  cast_bf16_kernel<<<4096, 256, 0, stream>>>(o_w, wo, 1048576);

  gemm_bt<1><<<dim3(32, 32), 256, 0, stream>>>(h_bf, wqkv, qkv, 4096, 4096, 2048);
  qknorm_kernel<<<16384, 256, 0, stream>>>(qkv, qnw, knw, Qb, Kb, Vt);

  // attn: 74752 B dynamic LDS (32KB K + 32KB V + 9KB P) -> 2 blocks/CU
  static const int ATTN_LDS = 74752;
  (void)hipFuncSetAttribute((const void*)attn_kernel,
                            hipFuncAttributeMaxDynamicSharedMemorySize, ATTN_LDS);
  attn_kernel<<<256, 256, ATTN_LDS, stream>>>(Qb, Kb, Vt, aout);

  gemm_bt<0><<<dim3(16, 32), 256, 0, stream>>>(aout, wo, d_out, 4096, 2048, 2048);
}